// Round 2
// baseline (693.272 us; speedup 1.0000x reference)
//
#include <hip/hip_runtime.h>
#include <math.h>

#define BB 4
#define CC 128
#define BT 32
#define NBOX 4
#define HH 256
#define WW 256
#define HW (HH*WW)
#define SP 257
#define SPLANE (SP*SP)
#define NPLANE (BB*BT)          // 128 integral-image planes
#define CHUNK 32                // rows per column-scan chunk
#define NCHUNK (HH/CHUNK)       // 8
#define ROWS 8                  // output rows per box_sample block
#define PF 16                   // channel prefetch depth in conv

// ---------------- Kernel A: 1x1 conv (128->32) + BN1 + row inclusive scan ----------------
// Block = one image row (b,i): 256 threads, one pixel each, 32 channels in registers.
// Grid caps occupancy at 4 waves/SIMD (1024 blocks), so each wave must self-hide
// HBM latency: explicit 16-deep register prefetch of the x channel stream gives
// ~1024 cycles of FMA per 16 in-flight loads (> ~900cy HBM latency).
// FMA order (c ascending, k inner) identical to previous version -> bitwise same.
__global__ __launch_bounds__(256, 4) void conv_bn1_scan(
        const float* __restrict__ x, const float* __restrict__ w1,
        const float* __restrict__ g1, const float* __restrict__ b1,
        const float* __restrict__ m1, const float* __restrict__ v1,
        float* __restrict__ t) {
    int pix = blockIdx.x * 256 + threadIdx.x;   // over B*HW
    int b  = pix >> 16;
    int ij = pix & 65535;
    const float* xb = x + b * (CC * HW) + ij;
    float acc[BT];
    #pragma unroll
    for (int k = 0; k < BT; ++k) acc[k] = 0.f;

    float cur[PF], nxt[PF];
    #pragma unroll
    for (int p = 0; p < PF; ++p) cur[p] = xb[p * HW];
    #pragma unroll
    for (int c0 = 0; c0 < CC - PF; c0 += PF) {
        #pragma unroll
        for (int p = 0; p < PF; ++p) nxt[p] = xb[(c0 + PF + p) * HW];
        #pragma unroll
        for (int p = 0; p < PF; ++p) {
            float xv = cur[p];
            #pragma unroll
            for (int k = 0; k < BT; ++k)
                acc[k] = fmaf(xv, w1[k * CC + (c0 + p)], acc[k]);
        }
        #pragma unroll
        for (int p = 0; p < PF; ++p) cur[p] = nxt[p];
    }
    #pragma unroll
    for (int p = 0; p < PF; ++p) {
        float xv = cur[p];
        #pragma unroll
        for (int k = 0; k < BT; ++k)
            acc[k] = fmaf(xv, w1[k * CC + (CC - PF + p)], acc[k]);
    }

    // BN1 (must precede the scan: reference scans bn1(conv) output)
    #pragma unroll
    for (int k = 0; k < BT; ++k) {
        float inv = g1[k] * __frsqrt_rn(v1[k] + 1e-5f);
        acc[k] = acc[k] * inv + (b1[k] - m1[k] * inv);
    }
    int lane = threadIdx.x & 63;
    int wave = threadIdx.x >> 6;
    // inclusive scan across 256 threads, all 32 channels in flight (step-outer for ILP)
    #pragma unroll
    for (int off = 1; off < 64; off <<= 1) {
        bool p = lane >= off;
        #pragma unroll
        for (int k = 0; k < BT; ++k) {
            float o = __shfl_up(acc[k], off, 64);
            if (p) acc[k] += o;
        }
    }
    __shared__ float wtot[3][BT];
    if (lane == 63 && wave < 3) {
        #pragma unroll
        for (int k = 0; k < BT; ++k) wtot[wave][k] = acc[k];
    }
    __syncthreads();
    float* tb = t + b * (BT * HW) + ij;
    #pragma unroll
    for (int k = 0; k < BT; ++k) {
        float off = 0.f;
        if (wave > 0) off += wtot[0][k];
        if (wave > 1) off += wtot[1][k];
        if (wave > 2) off += wtot[2][k];
        tb[k * HW] = acc[k] + off;
    }
}

// ---------------- Kernel B2a: per-chunk column partial sums ----------------
// grid = NPLANE*NCHUNK blocks of 256; thread = column j.
// Loads batched into registers (all 32 in flight), then summed in the SAME
// order as before (bitwise identical to serial version).
__global__ __launch_bounds__(256) void col_partial(const float* __restrict__ t,
                                                   float* __restrict__ T) {
    int plane = blockIdx.x >> 3;
    int chunk = blockIdx.x & 7;
    int j = threadIdx.x;
    const float* tp = t + (size_t)plane * HW + chunk * CHUNK * WW + j;
    float vals[CHUNK];
    #pragma unroll
    for (int r = 0; r < CHUNK; ++r) vals[r] = tp[r * WW];
    float s = 0.f;
    #pragma unroll
    for (int r = 0; r < CHUNK; ++r) s += vals[r];
    T[blockIdx.x * 256 + j] = s;
}

// ---------------- Kernel B2b: column scan with chunk offsets -> padded S ----------------
__global__ __launch_bounds__(256) void col_final(const float* __restrict__ t,
                                                 const float* __restrict__ T,
                                                 float* __restrict__ s) {
    int plane = blockIdx.x >> 3;
    int chunk = blockIdx.x & 7;
    int j = threadIdx.x;
    float off = 0.f;
    for (int c = 0; c < chunk; ++c) off += T[(plane * 8 + c) * 256 + j];
    const float* tp = t + (size_t)plane * HW + chunk * CHUNK * WW + j;
    float* sp = s + (size_t)plane * SPLANE;
    if (chunk == 0) {                    // top padding row
        sp[j + 1] = 0.f;
        if (j == 0) sp[0] = 0.f;
    }
    // batch the 32 strided loads so they overlap; accumulate order unchanged
    float vals[CHUNK];
    #pragma unroll
    for (int r = 0; r < CHUNK; ++r) vals[r] = tp[r * WW];
    float run = off;
    int rowbase = chunk * CHUNK;
    #pragma unroll
    for (int r = 0; r < CHUNK; ++r) {
        run += vals[r];
        sp[(size_t)(rowbase + r + 1) * SP + j + 1] = run;
        if (j == 0) sp[(size_t)(rowbase + r + 1) * SP] = 0.f;   // left padding col
    }
}

// ---------------- Kernel C: box sample via shared D-rows + BN2 + relus ----------------
// grid = B*BT*NBOX*(H/ROWS) blocks; each block produces ROWS=8 output rows.
// Each wave builds 2 D-rows into LDS; after one barrier every thread emits 8
// elements at column j, amortizing horizontal setup + BN2 scalars 8x.
__global__ __launch_bounds__(256) void box_sample(
        const float* __restrict__ s, const float* __restrict__ x,
        const float* __restrict__ xmin, const float* __restrict__ xmax,
        const float* __restrict__ ymin, const float* __restrict__ ymax,
        const float* __restrict__ g2, const float* __restrict__ b2,
        const float* __restrict__ m2, const float* __restrict__ v2,
        float* __restrict__ out) {
    __shared__ float D[ROWS][SP];
    int bid = blockIdx.x;
    int ig = bid & 31;                   // H/ROWS = 32 row-groups
    int n  = (bid >> 5) & 3;
    int k  = (bid >> 7) & 31;
    int b  = bid >> 12;
    int j  = threadIdx.x;
    int lane = j & 63;
    int wave = j >> 6;
    int kn = k * NBOX + n;
    int ibase = ig * ROWS;
    const float* sp = s + (size_t)(b * BT + k) * SPLANE;

    float xmn = xmin[kn], xmx = xmax[kn], ymn = ymin[kn], ymx = ymax[kn];

    // Each wave builds D rows {wave, wave+4}: D[r][v] = rowHi(v) - rowLo(v)
    #pragma unroll
    for (int rr = 0; rr < 2; ++rr) {
        int r = wave + rr * 4;
        float fi = (float)(ibase + r);
        float u_hi = fminf(fmaxf(fi + xmx, 0.f), 256.f);
        float u_lo = fminf(fmaxf(fi + xmn, 0.f), 256.f);
        int i1 = (int)fminf(floorf(u_hi), 255.f);
        int i0 = (int)fminf(floorf(u_lo), 255.f);
        float wu1 = u_hi - (float)i1;
        float wu0 = u_lo - (float)i0;
        const float* rA = sp + (size_t)i1 * SP;
        const float* rB = rA + SP;
        const float* rC = sp + (size_t)i0 * SP;
        const float* rD = rC + SP;
        #pragma unroll
        for (int tcol = 0; tcol < 4; ++tcol) {
            int c = lane + tcol * 64;
            D[r][c] = rA[c] * (1.f - wu1) + rB[c] * wu1
                    - rC[c] * (1.f - wu0) - rD[c] * wu0;
        }
        if (lane == 0) {
            int c = 256;
            D[r][c] = rA[c] * (1.f - wu1) + rB[c] * wu1
                    - rC[c] * (1.f - wu0) - rD[c] * wu0;
        }
    }
    __syncthreads();

    // horizontal setup: once per thread, reused for all 8 rows
    float v_hi = fminf(fmaxf((float)j + ymx, 0.f), 256.f);
    float v_lo = fminf(fmaxf((float)j + ymn, 0.f), 256.f);
    int j1 = (int)fminf(floorf(v_hi), 255.f);
    int j0 = (int)fminf(floorf(v_lo), 255.f);
    float wv1 = v_hi - (float)j1;
    float wv0 = v_lo - (float)j0;
    float cv1 = 1.f - wv1;
    float cv0 = 1.f - wv0;

    float inv = g2[kn] * __frsqrt_rn(v2[kn] + 1e-3f);
    float scale = inv * __frcp_rn((xmx - xmn) * (ymx - ymn));
    float add = b2[kn] - m2[kn] * inv;

    int obase = ((b * CC + kn) * HH + ibase) * WW + j;   // < 2^25, fits int
    const float* xp = x + obase;
    float* op = out + obase;
    #pragma unroll
    for (int r = 0; r < ROWS; ++r) {
        float hi = D[r][j1] * cv1 + D[r][j1 + 1] * wv1;
        float lo = D[r][j0] * cv0 + D[r][j0 + 1] * wv0;
        float val = (hi - lo) * scale + add;
        val = fmaxf(val, 0.f);                            // relu(bn2)
        float xv = __builtin_nontemporal_load(xp + r * WW);
        __builtin_nontemporal_store(fmaxf(xv + val, 0.f), op + r * WW);
    }
}

extern "C" void kernel_launch(void* const* d_in, const int* in_sizes, int n_in,
                              void* d_out, int out_size, void* d_ws, size_t ws_size,
                              hipStream_t stream) {
    const float* x    = (const float*)d_in[0];
    const float* w1   = (const float*)d_in[1];
    const float* g1   = (const float*)d_in[2];
    const float* b1   = (const float*)d_in[3];
    const float* m1   = (const float*)d_in[4];
    const float* v1   = (const float*)d_in[5];
    const float* xmin = (const float*)d_in[6];
    const float* xmax = (const float*)d_in[7];
    const float* ymin = (const float*)d_in[8];
    const float* ymax = (const float*)d_in[9];
    const float* g2   = (const float*)d_in[10];
    const float* b2   = (const float*)d_in[11];
    const float* m2   = (const float*)d_in[12];
    const float* v2   = (const float*)d_in[13];
    float* out = (float*)d_out;

    float* h = (float*)d_ws;                        // B*BT*HW floats (33.5 MB), row-scanned
    float* S = h + (size_t)BB * BT * HW;            // NPLANE*SPLANE floats (33.8 MB)
    float* T = S + (size_t)NPLANE * SPLANE;         // NPLANE*NCHUNK*256 floats (1 MB)

    conv_bn1_scan<<<(BB * HW) / 256, 256, 0, stream>>>(x, w1, g1, b1, m1, v1, h);
    col_partial  <<<NPLANE * NCHUNK, 256, 0, stream>>>(h, T);
    col_final    <<<NPLANE * NCHUNK, 256, 0, stream>>>(h, T, S);
    box_sample   <<<BB * BT * NBOX * (HH / ROWS), 256, 0, stream>>>(
                     S, x, xmin, xmax, ymin, ymax, g2, b2, m2, v2, out);
}

// Round 3
// 407.316 us; speedup vs baseline: 1.7020x; 1.7020x over previous
//
#include <hip/hip_runtime.h>
#include <math.h>

#define BB 4
#define CC 128
#define BT 32
#define NBOX 4
#define HH 256
#define WW 256
#define HW (HH*WW)
#define SP 257
#define SPLANE (SP*SP)
#define NPLANE (BB*BT)          // 128 integral-image planes
#define CHUNK 32                // rows per column-scan chunk
#define NCHUNK (HH/CHUNK)       // 8
#define ROWS 8                  // output rows per box_sample block
#define PF 8                    // channel prefetch depth in conv (ping-pong)

// ---------------- Kernel A: 1x1 conv (128->32) + BN1 + row inclusive scan ----------------
// Block = one image row (b,i): 256 threads, one pixel each, 32 channels in registers.
// Grid caps occupancy at 4 waves/SIMD (1024 blocks), so VGPR<=128 is free.
// PF=8 ping-pong register prefetch: acc[32]+bufA[8]+bufB[8]=48 live floats -> ~80 VGPR,
// no spills (NO __launch_bounds__ min-waves hint: round-2 showed it clamps to 64 VGPR
// and spills ~50MB to scratch).
// FMA order (c ascending, k inner) identical to previous versions -> bitwise same.
__global__ __launch_bounds__(256) void conv_bn1_scan(
        const float* __restrict__ x, const float* __restrict__ w1,
        const float* __restrict__ g1, const float* __restrict__ b1,
        const float* __restrict__ m1, const float* __restrict__ v1,
        float* __restrict__ t) {
    int pix = blockIdx.x * 256 + threadIdx.x;   // over B*HW
    int b  = pix >> 16;
    int ij = pix & 65535;
    const float* xb = x + b * (CC * HW) + ij;
    float acc[BT];
    #pragma unroll
    for (int k = 0; k < BT; ++k) acc[k] = 0.f;

    float bufA[PF], bufB[PF];
    #pragma unroll
    for (int p = 0; p < PF; ++p) bufA[p] = xb[p * HW];

    #pragma unroll
    for (int s = 0; s < CC / PF; s += 2) {      // 16 steps, unrolled in pairs
        // even step: prefetch into bufB, compute with bufA (channels s*PF..)
        if (s + 1 < CC / PF) {
            #pragma unroll
            for (int p = 0; p < PF; ++p) bufB[p] = xb[((s + 1) * PF + p) * HW];
        }
        #pragma unroll
        for (int p = 0; p < PF; ++p) {
            float xv = bufA[p];
            #pragma unroll
            for (int k = 0; k < BT; ++k)
                acc[k] = fmaf(xv, w1[k * CC + (s * PF + p)], acc[k]);
        }
        // odd step: prefetch into bufA, compute with bufB (channels (s+1)*PF..)
        if (s + 2 < CC / PF) {
            #pragma unroll
            for (int p = 0; p < PF; ++p) bufA[p] = xb[((s + 2) * PF + p) * HW];
        }
        #pragma unroll
        for (int p = 0; p < PF; ++p) {
            float xv = bufB[p];
            #pragma unroll
            for (int k = 0; k < BT; ++k)
                acc[k] = fmaf(xv, w1[k * CC + ((s + 1) * PF + p)], acc[k]);
        }
    }

    // BN1 (must precede the scan: reference scans bn1(conv) output)
    #pragma unroll
    for (int k = 0; k < BT; ++k) {
        float inv = g1[k] * __frsqrt_rn(v1[k] + 1e-5f);
        acc[k] = acc[k] * inv + (b1[k] - m1[k] * inv);
    }
    int lane = threadIdx.x & 63;
    int wave = threadIdx.x >> 6;
    // inclusive scan across 256 threads, all 32 channels in flight (step-outer for ILP)
    #pragma unroll
    for (int off = 1; off < 64; off <<= 1) {
        bool p = lane >= off;
        #pragma unroll
        for (int k = 0; k < BT; ++k) {
            float o = __shfl_up(acc[k], off, 64);
            if (p) acc[k] += o;
        }
    }
    __shared__ float wtot[3][BT];
    if (lane == 63 && wave < 3) {
        #pragma unroll
        for (int k = 0; k < BT; ++k) wtot[wave][k] = acc[k];
    }
    __syncthreads();
    float* tb = t + b * (BT * HW) + ij;
    #pragma unroll
    for (int k = 0; k < BT; ++k) {
        float off = 0.f;
        if (wave > 0) off += wtot[0][k];
        if (wave > 1) off += wtot[1][k];
        if (wave > 2) off += wtot[2][k];
        tb[k * HW] = acc[k] + off;
    }
}

// ---------------- Kernel B2a: per-chunk column partial sums ----------------
// grid = NPLANE*NCHUNK blocks of 256; thread = column j.
// Loads batched into registers (all 32 in flight), then summed in the SAME
// order as before (bitwise identical to serial version).
__global__ __launch_bounds__(256) void col_partial(const float* __restrict__ t,
                                                   float* __restrict__ T) {
    int plane = blockIdx.x >> 3;
    int chunk = blockIdx.x & 7;
    int j = threadIdx.x;
    const float* tp = t + (size_t)plane * HW + chunk * CHUNK * WW + j;
    float vals[CHUNK];
    #pragma unroll
    for (int r = 0; r < CHUNK; ++r) vals[r] = tp[r * WW];
    float s = 0.f;
    #pragma unroll
    for (int r = 0; r < CHUNK; ++r) s += vals[r];
    T[blockIdx.x * 256 + j] = s;
}

// ---------------- Kernel B2b: column scan with chunk offsets -> padded S ----------------
__global__ __launch_bounds__(256) void col_final(const float* __restrict__ t,
                                                 const float* __restrict__ T,
                                                 float* __restrict__ s) {
    int plane = blockIdx.x >> 3;
    int chunk = blockIdx.x & 7;
    int j = threadIdx.x;
    float off = 0.f;
    for (int c = 0; c < chunk; ++c) off += T[(plane * 8 + c) * 256 + j];
    const float* tp = t + (size_t)plane * HW + chunk * CHUNK * WW + j;
    float* sp = s + (size_t)plane * SPLANE;
    if (chunk == 0) {                    // top padding row
        sp[j + 1] = 0.f;
        if (j == 0) sp[0] = 0.f;
    }
    // batch the 32 strided loads so they overlap; accumulate order unchanged
    float vals[CHUNK];
    #pragma unroll
    for (int r = 0; r < CHUNK; ++r) vals[r] = tp[r * WW];
    float run = off;
    int rowbase = chunk * CHUNK;
    #pragma unroll
    for (int r = 0; r < CHUNK; ++r) {
        run += vals[r];
        sp[(size_t)(rowbase + r + 1) * SP + j + 1] = run;
        if (j == 0) sp[(size_t)(rowbase + r + 1) * SP] = 0.f;   // left padding col
    }
}

// ---------------- Kernel C: box sample via shared D-rows + BN2 + relus ----------------
// grid = B*BT*NBOX*(H/ROWS) blocks; each block produces ROWS=8 output rows.
// Each wave builds 2 D-rows into LDS; after one barrier every thread emits 8
// elements at column j, amortizing horizontal setup + BN2 scalars 8x.
__global__ __launch_bounds__(256) void box_sample(
        const float* __restrict__ s, const float* __restrict__ x,
        const float* __restrict__ xmin, const float* __restrict__ xmax,
        const float* __restrict__ ymin, const float* __restrict__ ymax,
        const float* __restrict__ g2, const float* __restrict__ b2,
        const float* __restrict__ m2, const float* __restrict__ v2,
        float* __restrict__ out) {
    __shared__ float D[ROWS][SP];
    int bid = blockIdx.x;
    int ig = bid & 31;                   // H/ROWS = 32 row-groups
    int n  = (bid >> 5) & 3;
    int k  = (bid >> 7) & 31;
    int b  = bid >> 12;
    int j  = threadIdx.x;
    int lane = j & 63;
    int wave = j >> 6;
    int kn = k * NBOX + n;
    int ibase = ig * ROWS;
    const float* sp = s + (size_t)(b * BT + k) * SPLANE;

    float xmn = xmin[kn], xmx = xmax[kn], ymn = ymin[kn], ymx = ymax[kn];

    // Each wave builds D rows {wave, wave+4}: D[r][v] = rowHi(v) - rowLo(v)
    #pragma unroll
    for (int rr = 0; rr < 2; ++rr) {
        int r = wave + rr * 4;
        float fi = (float)(ibase + r);
        float u_hi = fminf(fmaxf(fi + xmx, 0.f), 256.f);
        float u_lo = fminf(fmaxf(fi + xmn, 0.f), 256.f);
        int i1 = (int)fminf(floorf(u_hi), 255.f);
        int i0 = (int)fminf(floorf(u_lo), 255.f);
        float wu1 = u_hi - (float)i1;
        float wu0 = u_lo - (float)i0;
        const float* rA = sp + (size_t)i1 * SP;
        const float* rB = rA + SP;
        const float* rC = sp + (size_t)i0 * SP;
        const float* rD = rC + SP;
        #pragma unroll
        for (int tcol = 0; tcol < 4; ++tcol) {
            int c = lane + tcol * 64;
            D[r][c] = rA[c] * (1.f - wu1) + rB[c] * wu1
                    - rC[c] * (1.f - wu0) - rD[c] * wu0;
        }
        if (lane == 0) {
            int c = 256;
            D[r][c] = rA[c] * (1.f - wu1) + rB[c] * wu1
                    - rC[c] * (1.f - wu0) - rD[c] * wu0;
        }
    }
    __syncthreads();

    // horizontal setup: once per thread, reused for all 8 rows
    float v_hi = fminf(fmaxf((float)j + ymx, 0.f), 256.f);
    float v_lo = fminf(fmaxf((float)j + ymn, 0.f), 256.f);
    int j1 = (int)fminf(floorf(v_hi), 255.f);
    int j0 = (int)fminf(floorf(v_lo), 255.f);
    float wv1 = v_hi - (float)j1;
    float wv0 = v_lo - (float)j0;
    float cv1 = 1.f - wv1;
    float cv0 = 1.f - wv0;

    float inv = g2[kn] * __frsqrt_rn(v2[kn] + 1e-3f);
    float scale = inv * __frcp_rn((xmx - xmn) * (ymx - ymn));
    float add = b2[kn] - m2[kn] * inv;

    int obase = ((b * CC + kn) * HH + ibase) * WW + j;   // < 2^25, fits int
    const float* xp = x + obase;
    float* op = out + obase;
    #pragma unroll
    for (int r = 0; r < ROWS; ++r) {
        float hi = D[r][j1] * cv1 + D[r][j1 + 1] * wv1;
        float lo = D[r][j0] * cv0 + D[r][j0 + 1] * wv0;
        float val = (hi - lo) * scale + add;
        val = fmaxf(val, 0.f);                            // relu(bn2)
        float xv = __builtin_nontemporal_load(xp + r * WW);
        __builtin_nontemporal_store(fmaxf(xv + val, 0.f), op + r * WW);
    }
}

extern "C" void kernel_launch(void* const* d_in, const int* in_sizes, int n_in,
                              void* d_out, int out_size, void* d_ws, size_t ws_size,
                              hipStream_t stream) {
    const float* x    = (const float*)d_in[0];
    const float* w1   = (const float*)d_in[1];
    const float* g1   = (const float*)d_in[2];
    const float* b1   = (const float*)d_in[3];
    const float* m1   = (const float*)d_in[4];
    const float* v1   = (const float*)d_in[5];
    const float* xmin = (const float*)d_in[6];
    const float* xmax = (const float*)d_in[7];
    const float* ymin = (const float*)d_in[8];
    const float* ymax = (const float*)d_in[9];
    const float* g2   = (const float*)d_in[10];
    const float* b2   = (const float*)d_in[11];
    const float* m2   = (const float*)d_in[12];
    const float* v2   = (const float*)d_in[13];
    float* out = (float*)d_out;

    float* h = (float*)d_ws;                        // B*BT*HW floats (33.5 MB), row-scanned
    float* S = h + (size_t)BB * BT * HW;            // NPLANE*SPLANE floats (33.8 MB)
    float* T = S + (size_t)NPLANE * SPLANE;         // NPLANE*NCHUNK*256 floats (1 MB)

    conv_bn1_scan<<<(BB * HW) / 256, 256, 0, stream>>>(x, w1, g1, b1, m1, v1, h);
    col_partial  <<<NPLANE * NCHUNK, 256, 0, stream>>>(h, T);
    col_final    <<<NPLANE * NCHUNK, 256, 0, stream>>>(h, T, S);
    box_sample   <<<BB * BT * NBOX * (HH / ROWS), 256, 0, stream>>>(
                     S, x, xmin, xmax, ymin, ymax, g2, b2, m2, v2, out);
}

// Round 5
// 357.836 us; speedup vs baseline: 1.9374x; 1.1383x over previous
//
#include <hip/hip_runtime.h>
#include <math.h>

#define BB 4
#define CC 128
#define BT 32
#define NBOX 4
#define HH 256
#define WW 256
#define HW (HH*WW)
#define SP 257
#define SPLANE (SP*SP)
#define NPLANE (BB*BT)          // 128 integral-image planes
#define CHUNK 32                // rows per column-scan chunk
#define NCHUNK (HH/CHUNK)       // 8
#define ROWS 8                  // output rows per box_sample block
#define KH 16                   // output channels per conv block (split 32 -> 2x16)

// ---------------- Kernel A: 1x1 conv (128->16x2) + BN1 + row inclusive scan ----------------
// Latency-bound kernel; the lever is occupancy, not hand-ILP (rounds 2+3 both
// lost to the plain unrolled loop). Split each row into 2 blocks of KH=16
// output channels: 2048 blocks = 8 waves/SIMD (was 4). Demand ~36-45 VGPR;
// __launch_bounds__(256,8) caps at 64 (above demand -> no spill, unlike round 2
// where the cap was BELOW demand). Inner unroll=4 keeps the live window small;
// TLP (8 waves/SIMD) x ILP (4 loads) = 32 loads in flight per SIMD.
// Per-channel FMA order over c unchanged -> bitwise-identical output.
__global__ __launch_bounds__(256, 8) void conv_bn1_scan(
        const float* __restrict__ x, const float* __restrict__ w1,
        const float* __restrict__ g1, const float* __restrict__ b1,
        const float* __restrict__ m1, const float* __restrict__ v1,
        float* __restrict__ t) {
    int bid  = blockIdx.x;
    int half = bid & 1;                         // which 16-channel group
    int pix  = (bid >> 1) * 256 + threadIdx.x;  // over B*HW
    int b  = pix >> 16;
    int ij = pix & 65535;
    const float* xb = x + b * (CC * HW) + ij;
    const float* wb = w1 + half * KH * CC;
    float acc[KH];
    #pragma unroll
    for (int k = 0; k < KH; ++k) acc[k] = 0.f;
    #pragma unroll 4
    for (int c = 0; c < CC; ++c) {
        float xv = xb[c * HW];
        #pragma unroll
        for (int k = 0; k < KH; ++k)
            acc[k] = fmaf(xv, wb[k * CC + c], acc[k]);
    }
    // BN1 (must precede the scan: reference scans bn1(conv) output)
    #pragma unroll
    for (int k = 0; k < KH; ++k) {
        int k0 = half * KH + k;
        float inv = g1[k0] * __frsqrt_rn(v1[k0] + 1e-5f);
        acc[k] = acc[k] * inv + (b1[k0] - m1[k0] * inv);
    }
    int lane = threadIdx.x & 63;
    int wave = threadIdx.x >> 6;
    // inclusive scan across 256 threads, all 16 channels in flight
    #pragma unroll
    for (int off = 1; off < 64; off <<= 1) {
        bool p = lane >= off;
        #pragma unroll
        for (int k = 0; k < KH; ++k) {
            float o = __shfl_up(acc[k], off, 64);
            if (p) acc[k] += o;
        }
    }
    __shared__ float wtot[3][KH];
    if (lane == 63 && wave < 3) {
        #pragma unroll
        for (int k = 0; k < KH; ++k) wtot[wave][k] = acc[k];
    }
    __syncthreads();
    float* tb = t + b * (BT * HW) + half * KH * HW + ij;
    #pragma unroll
    for (int k = 0; k < KH; ++k) {
        float off = 0.f;
        if (wave > 0) off += wtot[0][k];
        if (wave > 1) off += wtot[1][k];
        if (wave > 2) off += wtot[2][k];
        tb[k * HW] = acc[k] + off;
    }
}

// ---------------- Kernel B2a: per-chunk column partial sums ----------------
// grid = NPLANE*NCHUNK blocks of 256; thread = column j.
// Loads batched into registers (all 32 in flight), then summed in the SAME
// order as before (bitwise identical to serial version).
__global__ __launch_bounds__(256) void col_partial(const float* __restrict__ t,
                                                   float* __restrict__ T) {
    int plane = blockIdx.x >> 3;
    int chunk = blockIdx.x & 7;
    int j = threadIdx.x;
    const float* tp = t + (size_t)plane * HW + chunk * CHUNK * WW + j;
    float vals[CHUNK];
    #pragma unroll
    for (int r = 0; r < CHUNK; ++r) vals[r] = tp[r * WW];
    float s = 0.f;
    #pragma unroll
    for (int r = 0; r < CHUNK; ++r) s += vals[r];
    T[blockIdx.x * 256 + j] = s;
}

// ---------------- Kernel B2b: column scan with chunk offsets -> padded S ----------------
__global__ __launch_bounds__(256) void col_final(const float* __restrict__ t,
                                                 const float* __restrict__ T,
                                                 float* __restrict__ s) {
    int plane = blockIdx.x >> 3;
    int chunk = blockIdx.x & 7;
    int j = threadIdx.x;
    float off = 0.f;
    for (int c = 0; c < chunk; ++c) off += T[(plane * 8 + c) * 256 + j];
    const float* tp = t + (size_t)plane * HW + chunk * CHUNK * WW + j;
    float* sp = s + (size_t)plane * SPLANE;
    if (chunk == 0) {                    // top padding row
        sp[j + 1] = 0.f;
        if (j == 0) sp[0] = 0.f;
    }
    // batch the 32 strided loads so they overlap; accumulate order unchanged
    float vals[CHUNK];
    #pragma unroll
    for (int r = 0; r < CHUNK; ++r) vals[r] = tp[r * WW];
    float run = off;
    int rowbase = chunk * CHUNK;
    #pragma unroll
    for (int r = 0; r < CHUNK; ++r) {
        run += vals[r];
        sp[(size_t)(rowbase + r + 1) * SP + j + 1] = run;
        if (j == 0) sp[(size_t)(rowbase + r + 1) * SP] = 0.f;   // left padding col
    }
}

// ---------------- Kernel C: box sample via shared D-rows + BN2 + relus ----------------
// grid = B*BT*NBOX*(H/ROWS) blocks; each block produces ROWS=8 output rows.
// Each wave builds 2 D-rows into LDS; after one barrier every thread emits 8
// elements at column j, amortizing horizontal setup + BN2 scalars 8x.
__global__ __launch_bounds__(256) void box_sample(
        const float* __restrict__ s, const float* __restrict__ x,
        const float* __restrict__ xmin, const float* __restrict__ xmax,
        const float* __restrict__ ymin, const float* __restrict__ ymax,
        const float* __restrict__ g2, const float* __restrict__ b2,
        const float* __restrict__ m2, const float* __restrict__ v2,
        float* __restrict__ out) {
    __shared__ float D[ROWS][SP];
    int bid = blockIdx.x;
    int ig = bid & 31;                   // H/ROWS = 32 row-groups
    int n  = (bid >> 5) & 3;
    int k  = (bid >> 7) & 31;
    int b  = bid >> 12;
    int j  = threadIdx.x;
    int lane = j & 63;
    int wave = j >> 6;
    int kn = k * NBOX + n;
    int ibase = ig * ROWS;
    const float* sp = s + (size_t)(b * BT + k) * SPLANE;

    float xmn = xmin[kn], xmx = xmax[kn], ymn = ymin[kn], ymx = ymax[kn];

    // Each wave builds D rows {wave, wave+4}: D[r][v] = rowHi(v) - rowLo(v)
    #pragma unroll
    for (int rr = 0; rr < 2; ++rr) {
        int r = wave + rr * 4;
        float fi = (float)(ibase + r);
        float u_hi = fminf(fmaxf(fi + xmx, 0.f), 256.f);
        float u_lo = fminf(fmaxf(fi + xmn, 0.f), 256.f);
        int i1 = (int)fminf(floorf(u_hi), 255.f);
        int i0 = (int)fminf(floorf(u_lo), 255.f);
        float wu1 = u_hi - (float)i1;
        float wu0 = u_lo - (float)i0;
        const float* rA = sp + (size_t)i1 * SP;
        const float* rB = rA + SP;
        const float* rC = sp + (size_t)i0 * SP;
        const float* rD = rC + SP;
        #pragma unroll
        for (int tcol = 0; tcol < 4; ++tcol) {
            int c = lane + tcol * 64;
            D[r][c] = rA[c] * (1.f - wu1) + rB[c] * wu1
                    - rC[c] * (1.f - wu0) - rD[c] * wu0;
        }
        if (lane == 0) {
            int c = 256;
            D[r][c] = rA[c] * (1.f - wu1) + rB[c] * wu1
                    - rC[c] * (1.f - wu0) - rD[c] * wu0;
        }
    }
    __syncthreads();

    // horizontal setup: once per thread, reused for all 8 rows
    float v_hi = fminf(fmaxf((float)j + ymx, 0.f), 256.f);
    float v_lo = fminf(fmaxf((float)j + ymn, 0.f), 256.f);
    int j1 = (int)fminf(floorf(v_hi), 255.f);
    int j0 = (int)fminf(floorf(v_lo), 255.f);
    float wv1 = v_hi - (float)j1;
    float wv0 = v_lo - (float)j0;
    float cv1 = 1.f - wv1;
    float cv0 = 1.f - wv0;

    float inv = g2[kn] * __frsqrt_rn(v2[kn] + 1e-3f);
    float scale = inv * __frcp_rn((xmx - xmn) * (ymx - ymn));
    float add = b2[kn] - m2[kn] * inv;

    int obase = ((b * CC + kn) * HH + ibase) * WW + j;   // < 2^25, fits int
    const float* xp = x + obase;
    float* op = out + obase;
    #pragma unroll
    for (int r = 0; r < ROWS; ++r) {
        float hi = D[r][j1] * cv1 + D[r][j1 + 1] * wv1;
        float lo = D[r][j0] * cv0 + D[r][j0 + 1] * wv0;
        float val = (hi - lo) * scale + add;
        val = fmaxf(val, 0.f);                            // relu(bn2)
        float xv = __builtin_nontemporal_load(xp + r * WW);
        __builtin_nontemporal_store(fmaxf(xv + val, 0.f), op + r * WW);
    }
}

extern "C" void kernel_launch(void* const* d_in, const int* in_sizes, int n_in,
                              void* d_out, int out_size, void* d_ws, size_t ws_size,
                              hipStream_t stream) {
    const float* x    = (const float*)d_in[0];
    const float* w1   = (const float*)d_in[1];
    const float* g1   = (const float*)d_in[2];
    const float* b1   = (const float*)d_in[3];
    const float* m1   = (const float*)d_in[4];
    const float* v1   = (const float*)d_in[5];
    const float* xmin = (const float*)d_in[6];
    const float* xmax = (const float*)d_in[7];
    const float* ymin = (const float*)d_in[8];
    const float* ymax = (const float*)d_in[9];
    const float* g2   = (const float*)d_in[10];
    const float* b2   = (const float*)d_in[11];
    const float* m2   = (const float*)d_in[12];
    const float* v2   = (const float*)d_in[13];
    float* out = (float*)d_out;

    float* h = (float*)d_ws;                        // B*BT*HW floats (33.5 MB), row-scanned
    float* S = h + (size_t)BB * BT * HW;            // NPLANE*SPLANE floats (33.8 MB)
    float* T = S + (size_t)NPLANE * SPLANE;         // NPLANE*NCHUNK*256 floats (1 MB)

    conv_bn1_scan<<<(BB * HW) / 256 * 2, 256, 0, stream>>>(x, w1, g1, b1, m1, v1, h);
    col_partial  <<<NPLANE * NCHUNK, 256, 0, stream>>>(h, T);
    col_final    <<<NPLANE * NCHUNK, 256, 0, stream>>>(h, T, S);
    box_sample   <<<BB * BT * NBOX * (HH / ROWS), 256, 0, stream>>>(
                     S, x, xmin, xmax, ymin, ymax, g2, b2, m2, v2, out);
}

// Round 6
// 327.752 us; speedup vs baseline: 2.1152x; 1.0918x over previous
//
#include <hip/hip_runtime.h>
#include <math.h>

#define BB 4
#define CC 128
#define BT 32
#define NBOX 4
#define HH 256
#define WW 256
#define HW (HH*WW)
#define SP 257
#define SPLANE (SP*SP)
#define NPLANE (BB*BT)          // 128 integral-image planes
#define CHUNK 32                // rows per column-scan chunk
#define NCHUNK (HH/CHUNK)       // 8
#define ROWS 8                  // output rows per box_sample block

// ---------------- Kernel A: 1x1 conv (128->32) + BN1 + row inclusive scan ----------------
// float4 over pixels: each thread owns 4 consecutive pixels, each wave owns one
// image row (64 lanes x 4 = 256). One wave-load = 1KB (4x the scalar version) ->
// bytes-in-flight fixes the latency-bound plateau (rounds 1-5: scalar loads
// capped at 1.2-1.6 TB/s regardless of occupancy). All 32 output channels per
// block: x read ONCE (round 5's channel split doubled FETCH to 131MB - no L3 merge).
// Row scan is per-wave (in-thread prefix + shfl_up), no LDS/barrier - identical
// association to round-0's row_scan kernel which passed at absmax 0.015625.
// Conv FMA order (c ascending, k inner, per pixel) unchanged.
// ~180 VGPR is free: grid (256 blocks) caps occupancy at 1 wave/SIMD, and per
// 4-channel group the wave issues 512 FMA-instr (~1024cy) > ~900cy HBM latency.
__global__ __launch_bounds__(256) void conv_bn1_scan(
        const float* __restrict__ x, const float* __restrict__ w1,
        const float* __restrict__ g1, const float* __restrict__ b1,
        const float* __restrict__ m1, const float* __restrict__ v1,
        float* __restrict__ t) {
    int p4 = blockIdx.x * 1024 + threadIdx.x * 4;   // first pixel of this thread's quad
    int b  = p4 >> 16;
    int ij = p4 & 65535;
    const float4* xb = (const float4*)(x + (size_t)b * (CC * HW) + ij);   // + c*(HW/4)
    float4 acc[BT];
    #pragma unroll
    for (int k = 0; k < BT; ++k) acc[k] = make_float4(0.f, 0.f, 0.f, 0.f);

    #pragma unroll 4
    for (int c = 0; c < CC; ++c) {
        float4 xv = xb[c * (HW / 4)];
        #pragma unroll
        for (int k = 0; k < BT; ++k) {
            float wv = w1[k * CC + c];
            acc[k].x = fmaf(xv.x, wv, acc[k].x);
            acc[k].y = fmaf(xv.y, wv, acc[k].y);
            acc[k].z = fmaf(xv.z, wv, acc[k].z);
            acc[k].w = fmaf(xv.w, wv, acc[k].w);
        }
    }

    // BN1 (must precede the scan: reference scans bn1(conv) output)
    #pragma unroll
    for (int k = 0; k < BT; ++k) {
        float inv = g1[k] * __frsqrt_rn(v1[k] + 1e-5f);
        float add = b1[k] - m1[k] * inv;
        acc[k].x = acc[k].x * inv + add;
        acc[k].y = acc[k].y * inv + add;
        acc[k].z = acc[k].z * inv + add;
        acc[k].w = acc[k].w * inv + add;
    }

    // per-wave row scan: in-thread prefix over 4, then 64-lane shfl scan
    int lane = threadIdx.x & 63;
    float4* tb = (float4*)(t + (size_t)b * (BT * HW) + ij);               // + k*(HW/4)
    #pragma unroll
    for (int k = 0; k < BT; ++k) {
        float4 v = acc[k];
        v.y += v.x; v.z += v.y; v.w += v.z;
        float tot = v.w;
        float sum = tot;
        #pragma unroll
        for (int off = 1; off < 64; off <<= 1) {
            float o = __shfl_up(sum, off, 64);
            if (lane >= off) sum += o;
        }
        float excl = sum - tot;
        v.x += excl; v.y += excl; v.z += excl; v.w += excl;
        tb[k * (HW / 4)] = v;
    }
}

// ---------------- Kernel B2a: per-chunk column partial sums ----------------
// grid = NPLANE*NCHUNK blocks of 256; thread = column j.
// Loads batched into registers (all 32 in flight), then summed in the SAME
// order as before (bitwise identical to serial version).
__global__ __launch_bounds__(256) void col_partial(const float* __restrict__ t,
                                                   float* __restrict__ T) {
    int plane = blockIdx.x >> 3;
    int chunk = blockIdx.x & 7;
    int j = threadIdx.x;
    const float* tp = t + (size_t)plane * HW + chunk * CHUNK * WW + j;
    float vals[CHUNK];
    #pragma unroll
    for (int r = 0; r < CHUNK; ++r) vals[r] = tp[r * WW];
    float s = 0.f;
    #pragma unroll
    for (int r = 0; r < CHUNK; ++r) s += vals[r];
    T[blockIdx.x * 256 + j] = s;
}

// ---------------- Kernel B2b: column scan with chunk offsets -> padded S ----------------
__global__ __launch_bounds__(256) void col_final(const float* __restrict__ t,
                                                 const float* __restrict__ T,
                                                 float* __restrict__ s) {
    int plane = blockIdx.x >> 3;
    int chunk = blockIdx.x & 7;
    int j = threadIdx.x;
    float off = 0.f;
    for (int c = 0; c < chunk; ++c) off += T[(plane * 8 + c) * 256 + j];
    const float* tp = t + (size_t)plane * HW + chunk * CHUNK * WW + j;
    float* sp = s + (size_t)plane * SPLANE;
    if (chunk == 0) {                    // top padding row
        sp[j + 1] = 0.f;
        if (j == 0) sp[0] = 0.f;
    }
    // batch the 32 strided loads so they overlap; accumulate order unchanged
    float vals[CHUNK];
    #pragma unroll
    for (int r = 0; r < CHUNK; ++r) vals[r] = tp[r * WW];
    float run = off;
    int rowbase = chunk * CHUNK;
    #pragma unroll
    for (int r = 0; r < CHUNK; ++r) {
        run += vals[r];
        sp[(size_t)(rowbase + r + 1) * SP + j + 1] = run;
        if (j == 0) sp[(size_t)(rowbase + r + 1) * SP] = 0.f;   // left padding col
    }
}

// ---------------- Kernel C: box sample via shared D-rows + BN2 + relus ----------------
// grid = B*BT*NBOX*(H/ROWS) blocks; each block produces ROWS=8 output rows.
// Each wave builds 2 D-rows into LDS; after one barrier every thread emits 8
// elements at column j, amortizing horizontal setup + BN2 scalars 8x.
__global__ __launch_bounds__(256) void box_sample(
        const float* __restrict__ s, const float* __restrict__ x,
        const float* __restrict__ xmin, const float* __restrict__ xmax,
        const float* __restrict__ ymin, const float* __restrict__ ymax,
        const float* __restrict__ g2, const float* __restrict__ b2,
        const float* __restrict__ m2, const float* __restrict__ v2,
        float* __restrict__ out) {
    __shared__ float D[ROWS][SP];
    int bid = blockIdx.x;
    int ig = bid & 31;                   // H/ROWS = 32 row-groups
    int n  = (bid >> 5) & 3;
    int k  = (bid >> 7) & 31;
    int b  = bid >> 12;
    int j  = threadIdx.x;
    int lane = j & 63;
    int wave = j >> 6;
    int kn = k * NBOX + n;
    int ibase = ig * ROWS;
    const float* sp = s + (size_t)(b * BT + k) * SPLANE;

    float xmn = xmin[kn], xmx = xmax[kn], ymn = ymin[kn], ymx = ymax[kn];

    // Each wave builds D rows {wave, wave+4}: D[r][v] = rowHi(v) - rowLo(v)
    #pragma unroll
    for (int rr = 0; rr < 2; ++rr) {
        int r = wave + rr * 4;
        float fi = (float)(ibase + r);
        float u_hi = fminf(fmaxf(fi + xmx, 0.f), 256.f);
        float u_lo = fminf(fmaxf(fi + xmn, 0.f), 256.f);
        int i1 = (int)fminf(floorf(u_hi), 255.f);
        int i0 = (int)fminf(floorf(u_lo), 255.f);
        float wu1 = u_hi - (float)i1;
        float wu0 = u_lo - (float)i0;
        const float* rA = sp + (size_t)i1 * SP;
        const float* rB = rA + SP;
        const float* rC = sp + (size_t)i0 * SP;
        const float* rD = rC + SP;
        #pragma unroll
        for (int tcol = 0; tcol < 4; ++tcol) {
            int c = lane + tcol * 64;
            D[r][c] = rA[c] * (1.f - wu1) + rB[c] * wu1
                    - rC[c] * (1.f - wu0) - rD[c] * wu0;
        }
        if (lane == 0) {
            int c = 256;
            D[r][c] = rA[c] * (1.f - wu1) + rB[c] * wu1
                    - rC[c] * (1.f - wu0) - rD[c] * wu0;
        }
    }
    __syncthreads();

    // horizontal setup: once per thread, reused for all 8 rows
    float v_hi = fminf(fmaxf((float)j + ymx, 0.f), 256.f);
    float v_lo = fminf(fmaxf((float)j + ymn, 0.f), 256.f);
    int j1 = (int)fminf(floorf(v_hi), 255.f);
    int j0 = (int)fminf(floorf(v_lo), 255.f);
    float wv1 = v_hi - (float)j1;
    float wv0 = v_lo - (float)j0;
    float cv1 = 1.f - wv1;
    float cv0 = 1.f - wv0;

    float inv = g2[kn] * __frsqrt_rn(v2[kn] + 1e-3f);
    float scale = inv * __frcp_rn((xmx - xmn) * (ymx - ymn));
    float add = b2[kn] - m2[kn] * inv;

    int obase = ((b * CC + kn) * HH + ibase) * WW + j;   // < 2^25, fits int
    const float* xp = x + obase;
    float* op = out + obase;
    #pragma unroll
    for (int r = 0; r < ROWS; ++r) {
        float hi = D[r][j1] * cv1 + D[r][j1 + 1] * wv1;
        float lo = D[r][j0] * cv0 + D[r][j0 + 1] * wv0;
        float val = (hi - lo) * scale + add;
        val = fmaxf(val, 0.f);                            // relu(bn2)
        float xv = __builtin_nontemporal_load(xp + r * WW);
        __builtin_nontemporal_store(fmaxf(xv + val, 0.f), op + r * WW);
    }
}

extern "C" void kernel_launch(void* const* d_in, const int* in_sizes, int n_in,
                              void* d_out, int out_size, void* d_ws, size_t ws_size,
                              hipStream_t stream) {
    const float* x    = (const float*)d_in[0];
    const float* w1   = (const float*)d_in[1];
    const float* g1   = (const float*)d_in[2];
    const float* b1   = (const float*)d_in[3];
    const float* m1   = (const float*)d_in[4];
    const float* v1   = (const float*)d_in[5];
    const float* xmin = (const float*)d_in[6];
    const float* xmax = (const float*)d_in[7];
    const float* ymin = (const float*)d_in[8];
    const float* ymax = (const float*)d_in[9];
    const float* g2   = (const float*)d_in[10];
    const float* b2   = (const float*)d_in[11];
    const float* m2   = (const float*)d_in[12];
    const float* v2   = (const float*)d_in[13];
    float* out = (float*)d_out;

    float* h = (float*)d_ws;                        // B*BT*HW floats (33.5 MB), row-scanned
    float* S = h + (size_t)BB * BT * HW;            // NPLANE*SPLANE floats (33.8 MB)
    float* T = S + (size_t)NPLANE * SPLANE;         // NPLANE*NCHUNK*256 floats (1 MB)

    conv_bn1_scan<<<(BB * HW) / 1024, 256, 0, stream>>>(x, w1, g1, b1, m1, v1, h);
    col_partial  <<<NPLANE * NCHUNK, 256, 0, stream>>>(h, T);
    col_final    <<<NPLANE * NCHUNK, 256, 0, stream>>>(h, T, S);
    box_sample   <<<BB * BT * NBOX * (HH / ROWS), 256, 0, stream>>>(
                     S, x, xmin, xmax, ymin, ymax, g2, b2, m2, v2, out);
}